// Round 19
// baseline (44.414 us; speedup 1.0000x reference)
//
#include <hip/hip_runtime.h>

typedef unsigned short ushort_t;
typedef unsigned int uint_t;

constexpr int BSZ = 32;
constexpr int CH  = 64;
constexpr int HW  = 32 * 128;   // 4096
constexpr int NP  = 512;
constexpr float EPS = 1e-8f;
constexpr float SCL = 2.8853900817779268f;   // 2*log2(e): pre-scale W,QB -> tanh needs no mul
constexpr float L2E = 1.4426950408889634f;   // log2(e)

using f16x8 = __attribute__((ext_vector_type(8))) _Float16;  // 8 fp16 (4 VGPRs)
using f32x4 = __attribute__((ext_vector_type(4))) float;

// async global->LDS (LDS dest = wave-uniform base + lane*size)
__device__ __forceinline__ void gld16(const void* g, void* l) {
    __builtin_amdgcn_global_load_lds(
        (const __attribute__((address_space(1))) void*)g,
        (__attribute__((address_space(3))) void*)l, 16, 0, 0);
}

// K0: W' = SCL*Ua_w as single-pass fp16 in MFMA-frag order (r18-proven:
// absmax 6.1e-5, 3.2x under threshold).
//   fidx = mt*1024 + ks*512 + (kg*16+lm)*8 + j   (mt = o>>4 = 0..31)
// QB = SCL*(query+Ua_b); Va2 = -2*Va_w; SUMVW = sum(Va_w).
__global__ __launch_bounds__(256) void k_prep(
    const float* __restrict__ Ua_w, const float* __restrict__ Ua_b,
    const float* __restrict__ query, const float* __restrict__ Va_w,
    ushort_t* __restrict__ Whf,
    float* __restrict__ QB, float* __restrict__ Va2, float* __restrict__ SUMVW)
{
    const int i = blockIdx.x * 256 + threadIdx.x;
    if (i < NP * CH) {
        const int o = i >> 6, ch = i & 63;
        const int mt = o >> 4, lm = o & 15;
        const int ks = ch >> 5, kg = (ch >> 3) & 3, j = ch & 7;
        const int fidx = mt * 1024 + ks * 512 + (kg * 16 + lm) * 8 + j;
        _Float16 h = (_Float16)(Ua_w[i] * SCL);
        Whf[fidx] = __builtin_bit_cast(ushort_t, h);
    }
    if (i < BSZ * NP) {
        QB[i] = SCL * (query[i] + Ua_b[i & (NP - 1)]);
    }
    if (i < NP) {
        Va2[i] = -2.0f * Va_w[i];
    }
    if (blockIdx.x == 0 && threadIdx.x < 64) {
        float s = 0.0f;
#pragma unroll
        for (int t = 0; t < 8; ++t) s += Va_w[threadIdx.x + t * 64];
#pragma unroll
        for (int off = 32; off > 0; off >>= 1) s += __shfl_down(s, off, 64);
        if (threadIdx.x == 0) SUMVW[0] = s;
    }
}

// K1: FULL logit + exp + per-block denominator partial in ONE kernel.
// r18 post-mortem: fp16 shrank W to 64KB, so a 512-thread block (8 waves =
// 4 o-quarters x 2 position-halves) holds ALL 512 o in LDS (71.7KB -> 2
// blocks/CU = 16 waves/CU, same as r18). Kills k_denom (was 32-block,
// 12.5%-occupancy) and the 4MB e_part round-trip. Quarters combine via 2KB
// LDS; exp + dsum fused here; k_scale folds the 32 dsum entries.
// XCD swizzle: bx%8 == b%8 -> each XCD's L2 caches 4 b's of key = 4MB.
// Per-wave inner loop identical to r18 (8 MFMA/mt, setprio, sleep stagger).
__global__ __launch_bounds__(512, 4) void k_scores(
    const float* __restrict__ key,
    const ushort_t* __restrict__ Whf,
    const float* __restrict__ QB, const float* __restrict__ Va2,
    const float* __restrict__ SUMVW, const float* __restrict__ Va_b,
    float* __restrict__ e_exp, float* __restrict__ dsum)
{
    const int bx = blockIdx.x;            // 0..1023
    const int inner = bx >> 3;
    const int b  = (bx & 7) + 8 * (inner >> 5);   // same-b blocks: same XCD
    const int pc = inner & 31;            // 128-pos chunk
    const int tid = threadIdx.x;
    const int wv = tid >> 6;              // 0..7
    const int r  = wv & 3;                // o-quarter
    const int ws = wv >> 2;               // position half (0,1)
    const int l  = tid & 63;
    const int lm = l & 15;                // col-in-tile (A row / B,C col)
    const int kg = l >> 4;                // k-group
    const int p0 = pc * 128 + ws * 64;    // wave's first position

    __shared__ ushort_t Wl[32768];        // FULL W fp16 frag order (64KB)
    __shared__ float qbl[NP];
    __shared__ float vwl[NP];
    __shared__ float comb[4][128];
    __shared__ float wsum[2];

    // ---- stage full W: wave wv stages ushorts [wv*4096, +4096) (8KB) ----
#pragma unroll
    for (int t = 0; t < 8; ++t)
        gld16(Whf + wv * 4096 + t * 512 + l * 8, &Wl[wv * 4096 + t * 512]);
    if (wv == 0) {                        // qb: 512 floats
        gld16(QB + b * NP + l * 4,       &qbl[0]);
        gld16(QB + b * NP + 256 + l * 4, &qbl[256]);
    }
    if (wv == 1) {                        // vw (= -2*Va_w): 512 floats
        gld16(Va2 + l * 4,       &vwl[0]);
        gld16(Va2 + 256 + l * 4, &vwl[256]);
    }

    // ---- load + fp16-convert this wave's key: B = key[b,:,p0..p0+63] ----
    f16x8 Bf[4][2];
    const float* kb = key + (size_t)b * CH * HW;
#pragma unroll
    for (int nt = 0; nt < 4; ++nt) {
#pragma unroll
        for (int ks = 0; ks < 2; ++ks) {
#pragma unroll
            for (int j = 0; j < 8; ++j) {
                float xv = kb[(size_t)(ks * 32 + kg * 8 + j) * HW + (p0 + nt * 16 + lm)];
                Bf[nt][ks][j] = (_Float16)xv;
            }
        }
    }

    __syncthreads();                      // all staging drained

    // time-domain stagger: de-phase the 8 waves (~190 cyc apart)
    if (wv == 1) __builtin_amdgcn_s_sleep(3);
    else if (wv == 2) __builtin_amdgcn_s_sleep(6);
    else if (wv == 3) __builtin_amdgcn_s_sleep(9);
    else if (wv == 4) __builtin_amdgcn_s_sleep(12);
    else if (wv == 5) __builtin_amdgcn_s_sleep(15);
    else if (wv == 6) __builtin_amdgcn_s_sleep(18);
    else if (wv == 7) __builtin_amdgcn_s_sleep(21);

    float P[4] = {0.0f, 0.0f, 0.0f, 0.0f};   // partial of (-2vw)*rcp

    // ---- this wave's 8 m-tiles (o-quarter r), no barriers, no global ops ----
#pragma unroll 2
    for (int mt = 0; mt < 8; ++mt) {
        const int mg = r * 8 + mt;        // global m-tile 0..31
        const f16x8 Ah0 = *(const f16x8*)&Wl[mg * 1024 + l * 8];
        const f16x8 Ah1 = *(const f16x8*)&Wl[mg * 1024 + 512 + l * 8];
        const f32x4 qb = *(const f32x4*)&qbl[mg * 16 + kg * 4];
        const f32x4 vw = *(const f32x4*)&vwl[mg * 16 + kg * 4];

        // 4 independent chains of depth 2; C-init = qb
        f32x4 acc[4];
        __builtin_amdgcn_s_setprio(1);
#pragma unroll
        for (int nt = 0; nt < 4; ++nt)
            acc[nt] = __builtin_amdgcn_mfma_f32_16x16x32_f16(Ah0, Bf[nt][0], qb, 0, 0, 0);
#pragma unroll
        for (int nt = 0; nt < 4; ++nt)
            acc[nt] = __builtin_amdgcn_mfma_f32_16x16x32_f16(Ah1, Bf[nt][1], acc[nt], 0, 0, 0);
        __builtin_amdgcn_s_setprio(0);

        // epilogue: s pre-scaled by 2*log2(e); P += (-2vw)*rcp(exp2(s)+1)
#pragma unroll
        for (int nt = 0; nt < 4; ++nt)
#pragma unroll
            for (int rr = 0; rr < 4; ++rr) {
                float e  = __builtin_amdgcn_exp2f(acc[nt][rr]);
                float rc = __builtin_amdgcn_rcpf(e + 1.0f);
                P[nt] = fmaf(vw[rr], rc, P[nt]);
            }
    }

    // reduce over the 4 k-groups; write this quarter's 64 positions to LDS
#pragma unroll
    for (int nt = 0; nt < 4; ++nt) {
        P[nt] += __shfl_xor(P[nt], 16, 64);
        P[nt] += __shfl_xor(P[nt], 32, 64);
    }
    if (kg == 0) {
#pragma unroll
        for (int nt = 0; nt < 4; ++nt)
            comb[r][ws * 64 + nt * 16 + lm] = P[nt];
    }
    __syncthreads();

    // ---- combine quarters, exp, write e_exp, block partial denominator ----
    const float base = SUMVW[0] + Va_b[0];
    if (wv < 2) {
        const int p = wv * 64 + l;        // position within the 128-chunk
        float e = __builtin_amdgcn_exp2f(
            (((comb[0][p] + comb[1][p]) + (comb[2][p] + comb[3][p])) + base) * L2E);
        e_exp[(size_t)b * HW + pc * 128 + p] = e;
        float ee = e;
#pragma unroll
        for (int off = 32; off > 0; off >>= 1) ee += __shfl_down(ee, off, 64);
        if (l == 0) wsum[wv] = ee;
    }
    __syncthreads();
    if (tid == 0) dsum[b * 32 + pc] = wsum[0] + wsum[1];
}

// K2: out[b,c,p] = feature[b,c,p] * e_exp[b,p] / (sum dsum[b,:] + EPS)
__global__ __launch_bounds__(256) void k_scale(
    const float* __restrict__ feature,
    const float* __restrict__ e_exp,
    const float* __restrict__ dsum,
    float* __restrict__ out)
{
    const int idx = blockIdx.x * 256 + threadIdx.x;   // float4 index
    const int pq = idx & (HW / 4 - 1);
    const int bc = idx >> 10;
    const int b  = bc >> 6;                            // block-uniform

    float dsm = EPS;
#pragma unroll
    for (int i = 0; i < 32; ++i) dsm += dsum[b * 32 + i];   // uniform s_loads
    const float sc = 1.0f / dsm;

    const float4 e = ((const float4*)(e_exp + (size_t)b * HW))[pq];
    const float4 f = ((const float4*)feature)[idx];
    float4 o;
    o.x = f.x * (e.x * sc);
    o.y = f.y * (e.y * sc);
    o.z = f.z * (e.z * sc);
    o.w = f.w * (e.w * sc);
    ((float4*)out)[idx] = o;
}

extern "C" void kernel_launch(void* const* d_in, const int* in_sizes, int n_in,
                              void* d_out, int out_size, void* d_ws, size_t ws_size,
                              hipStream_t stream)
{
    const float* feature = (const float*)d_in[0];
    const float* query   = (const float*)d_in[1];
    const float* key     = (const float*)d_in[2];
    const float* Ua_w    = (const float*)d_in[3];
    const float* Ua_b    = (const float*)d_in[4];
    const float* Va_w    = (const float*)d_in[5];
    const float* Va_b    = (const float*)d_in[6];

    // workspace layout
    ushort_t* Whf    = (ushort_t*)d_ws;                     // 512*64 fp16 frag-order
    float* QB        = (float*)(Whf + NP * CH);             // 32*512
    float* Va2       = QB + BSZ * NP;                       // 512
    float* SUMVW     = Va2 + NP;                            // 1 (+pad)
    float* e_exp     = SUMVW + 4;                           // 32*4096
    float* dsum      = e_exp + BSZ * HW;                    // 32*32

    k_prep<<<(NP * CH) / 256, 256, 0, stream>>>(
        Ua_w, Ua_b, query, Va_w, Whf, QB, Va2, SUMVW);
    k_scores<<<BSZ * 32, 512, 0, stream>>>(
        key, Whf, QB, Va2, SUMVW, Va_b, e_exp, dsum);
    k_scale<<<(BSZ * CH * HW / 4) / 256, 256, 0, stream>>>(
        feature, e_exp, dsum, (float*)d_out);
}

// Round 20
// 40.991 us; speedup vs baseline: 1.0835x; 1.0835x over previous
//
#include <hip/hip_runtime.h>

typedef unsigned short ushort_t;
typedef unsigned int uint_t;

constexpr int BSZ = 32;
constexpr int CH  = 64;
constexpr int HW  = 32 * 128;   // 4096
constexpr int NP  = 512;
constexpr int OSPLIT = 4;             // o-split across blocks
constexpr int OCHUNK = NP / OSPLIT;   // 128 o per block = 8 m-tiles
constexpr int MT     = OCHUNK / 16;   // 8
constexpr float EPS = 1e-8f;
constexpr float SCL = 2.8853900817779268f;   // 2*log2(e): pre-scale W,QB -> tanh needs no mul
constexpr float L2E = 1.4426950408889634f;   // log2(e)

using f16x8 = __attribute__((ext_vector_type(8))) _Float16;  // 8 fp16 (4 VGPRs)
using f32x4 = __attribute__((ext_vector_type(4))) float;

// async global->LDS (LDS dest = wave-uniform base + lane*size)
__device__ __forceinline__ void gld16(const void* g, void* l) {
    __builtin_amdgcn_global_load_lds(
        (const __attribute__((address_space(1))) void*)g,
        (__attribute__((address_space(3))) void*)l, 16, 0, 0);
}
__device__ __forceinline__ void gld4(const void* g, void* l) {
    __builtin_amdgcn_global_load_lds(
        (const __attribute__((address_space(1))) void*)g,
        (__attribute__((address_space(3))) void*)l, 4, 0, 0);
}

// K0: W' = SCL*Ua_w as single-pass fp16 in MFMA-frag order (r18-proven:
// absmax 6.1e-5, 3.2x under threshold).
//   fidx = mt*1024 + ks*512 + (kg*16+lm)*8 + j   (mt = o>>4 = 0..31)
// QB = SCL*(query+Ua_b); Va2 = -2*Va_w; SUMVW = sum(Va_w).
__global__ __launch_bounds__(256) void k_prep(
    const float* __restrict__ Ua_w, const float* __restrict__ Ua_b,
    const float* __restrict__ query, const float* __restrict__ Va_w,
    ushort_t* __restrict__ Whf,
    float* __restrict__ QB, float* __restrict__ Va2, float* __restrict__ SUMVW)
{
    const int i = blockIdx.x * 256 + threadIdx.x;
    if (i < NP * CH) {
        const int o = i >> 6, ch = i & 63;
        const int mt = o >> 4, lm = o & 15;
        const int ks = ch >> 5, kg = (ch >> 3) & 3, j = ch & 7;
        const int fidx = mt * 1024 + ks * 512 + (kg * 16 + lm) * 8 + j;
        _Float16 h = (_Float16)(Ua_w[i] * SCL);
        Whf[fidx] = __builtin_bit_cast(ushort_t, h);
    }
    if (i < BSZ * NP) {
        QB[i] = SCL * (query[i] + Ua_b[i & (NP - 1)]);
    }
    if (i < NP) {
        Va2[i] = -2.0f * Va_w[i];
    }
    if (blockIdx.x == 0 && threadIdx.x < 64) {
        float s = 0.0f;
#pragma unroll
        for (int t = 0; t < 8; ++t) s += Va_w[threadIdx.x + t * 64];
#pragma unroll
        for (int off = 32; off > 0; off >>= 1) s += __shfl_down(s, off, 64);
        if (threadIdx.x == 0) SUMVW[0] = s;
    }
}

// K1: partial tanh-sums over an o-quarter, single-pass fp16 MFMA.
// == r18 byte-for-byte (41.75us total, prediction matched; r19's fusion
// dropped residency 32->16 waves/CU and regressed). 8 blocks/CU, 1 barrier,
// s_sleep stagger, setprio on MFMA, XCD grouping.
__global__ __launch_bounds__(256, 4) void k_scores(
    const float* __restrict__ key,
    const ushort_t* __restrict__ Whf,
    const float* __restrict__ QB, const float* __restrict__ Va2,
    float* __restrict__ e_part)
{
    const int bx = blockIdx.x;            // 0..2047
    const int x  = bx & 7;                // XCD slot
    const int r  = (bx >> 3) & 3;         // o-quarter (siblings 8 apart: same XCD)
    const int g  = (bx >> 5) * 8 + x;     // (b,pc) group 0..511
    const int b  = g >> 4;                // batch
    const int pc = g & 15;                // 256-pos chunk
    const int wv = threadIdx.x >> 6;
    const int l  = threadIdx.x & 63;
    const int lm = l & 15;                // col-in-tile (A row / B,C col)
    const int kg = l >> 4;                // k-group
    const int p0 = pc * 256 + wv * 64;    // wave's first position

    __shared__ ushort_t Wl[8192];         // this r's 8 m-tiles, fp16 frag order (16KB)
    __shared__ float qbl[OCHUNK];
    __shared__ float vwl[OCHUNK];

    // ---- stage W quarter: wave wv stages m-tiles {wv*2, wv*2+1} ----
    const size_t wbase = ((size_t)r * MT + wv * 2) * 1024;   // ushort offset
#pragma unroll
    for (int t = 0; t < 4; ++t)
        gld16(Whf + wbase + t * 512 + l * 8, &Wl[wv * 2048 + t * 512]);
    if (wv == 0) {                        // qb quarter: 128 floats
        gld4(QB + b * NP + r * OCHUNK + l, &qbl[0]);
        gld4(QB + b * NP + r * OCHUNK + 64 + l, &qbl[64]);
    }
    if (wv == 1) {                        // vw quarter: 128 floats
        gld4(Va2 + r * OCHUNK + l, &vwl[0]);
        gld4(Va2 + r * OCHUNK + 64 + l, &vwl[64]);
    }

    // ---- load + fp16-convert this wave's key ONCE: B = key[b,:,p0..p0+63] ----
    f16x8 Bh[4][2];
    const float* kb = key + (size_t)b * CH * HW;
#pragma unroll
    for (int nt = 0; nt < 4; ++nt) {
#pragma unroll
        for (int ks = 0; ks < 2; ++ks) {
#pragma unroll
            for (int j = 0; j < 8; ++j) {
                float xv = kb[(size_t)(ks * 32 + kg * 8 + j) * HW + (p0 + nt * 16 + lm)];
                Bh[nt][ks][j] = (_Float16)xv;
            }
        }
    }

    __syncthreads();                      // all staging drained; ONLY barrier

    // time-domain stagger: de-phase the block's waves (~320 cyc apart)
    if (wv == 1) __builtin_amdgcn_s_sleep(5);
    else if (wv == 2) __builtin_amdgcn_s_sleep(10);
    else if (wv == 3) __builtin_amdgcn_s_sleep(15);

    float P[4] = {0.0f, 0.0f, 0.0f, 0.0f};   // partial of (-2vw)*rcp

    // ---- 8 m-tiles, no barriers, no global ops ----
#pragma unroll 2
    for (int mt = 0; mt < MT; ++mt) {
        const f16x8 Ah0 = *(const f16x8*)&Wl[mt * 1024 + l * 8];
        const f16x8 Ah1 = *(const f16x8*)&Wl[mt * 1024 + 512 + l * 8];
        const f32x4 qb = *(const f32x4*)&qbl[mt * 16 + kg * 4];
        const f32x4 vw = *(const f32x4*)&vwl[mt * 16 + kg * 4];

        // 4 independent chains of depth 2; C-init = qb
        f32x4 acc[4];
        __builtin_amdgcn_s_setprio(1);
#pragma unroll
        for (int nt = 0; nt < 4; ++nt)
            acc[nt] = __builtin_amdgcn_mfma_f32_16x16x32_f16(Ah0, Bh[nt][0], qb, 0, 0, 0);
#pragma unroll
        for (int nt = 0; nt < 4; ++nt)
            acc[nt] = __builtin_amdgcn_mfma_f32_16x16x32_f16(Ah1, Bh[nt][1], acc[nt], 0, 0, 0);
        __builtin_amdgcn_s_setprio(0);

        // epilogue: s pre-scaled by 2*log2(e); P += (-2vw)*rcp(exp2(s)+1)
#pragma unroll
        for (int nt = 0; nt < 4; ++nt)
#pragma unroll
            for (int rr = 0; rr < 4; ++rr) {
                float e  = __builtin_amdgcn_exp2f(acc[nt][rr]);
                float rc = __builtin_amdgcn_rcpf(e + 1.0f);
                P[nt] = fmaf(vw[rr], rc, P[nt]);
            }
    }

    // reduce over the 4 k-groups; kg==0 lanes hold the quarter-sums
#pragma unroll
    for (int nt = 0; nt < 4; ++nt) {
        P[nt] += __shfl_xor(P[nt], 16, 64);
        P[nt] += __shfl_xor(P[nt], 32, 64);
    }
    if (kg == 0) {
        float* dst = e_part + (size_t)r * (BSZ * HW) + (size_t)b * HW + p0;
#pragma unroll
        for (int nt = 0; nt < 4; ++nt)
            dst[nt * 16 + lm] = P[nt];
    }
}

// K2: combine 4 o-quarters, exp, PARTIAL denominator.
// r18's k_denom was 32 blocks = 12.5% of CUs, latency-bound ~3.5us. Now 256
// blocks (32 b x 8 chunks of 512 positions) -> dsum[b*8+c]; k_scale folds 8.
__global__ __launch_bounds__(256) void k_denom(
    const float* __restrict__ e_part,
    const float* __restrict__ SUMVW, const float* __restrict__ Va_b,
    float* __restrict__ e_exp, float* __restrict__ dsum)
{
    const int b  = blockIdx.x >> 3;       // batch
    const int c  = blockIdx.x & 7;        // 512-pos chunk
    const int tid = threadIdx.x;
    const float base = SUMVW[0] + Va_b[0];
    float s = 0.0f;
#pragma unroll
    for (int i = 0; i < 2; ++i) {
        const int idx = b * HW + c * 512 + i * 256 + tid;
        float p = (e_part[idx] + e_part[BSZ * HW + idx]) +
                  (e_part[2 * BSZ * HW + idx] + e_part[3 * BSZ * HW + idx]);
        float e = __builtin_amdgcn_exp2f((p + base) * L2E);
        e_exp[idx] = e;
        s += e;
    }
#pragma unroll
    for (int off = 32; off > 0; off >>= 1) s += __shfl_down(s, off, 64);
    __shared__ float wsum[4];
    if ((tid & 63) == 0) wsum[tid >> 6] = s;
    __syncthreads();
    if (tid == 0)
        dsum[blockIdx.x] = (wsum[0] + wsum[1]) + (wsum[2] + wsum[3]);
}

// K3: out[b,c,p] = feature[b,c,p] * e_exp[b,p] / (sum_8 dsum[b*8+i] + EPS)
__global__ __launch_bounds__(256) void k_scale(
    const float* __restrict__ feature,
    const float* __restrict__ e_exp,
    const float* __restrict__ dsum,
    float* __restrict__ out)
{
    const int idx = blockIdx.x * 256 + threadIdx.x;   // float4 index
    const int pq = idx & (HW / 4 - 1);
    const int bc = idx >> 10;
    const int b  = bc >> 6;                            // block-uniform

    float dsm = EPS;
#pragma unroll
    for (int i = 0; i < 8; ++i) dsm += dsum[b * 8 + i];   // uniform s_loads
    const float sc = 1.0f / dsm;

    const float4 e = ((const float4*)(e_exp + (size_t)b * HW))[pq];
    const float4 f = ((const float4*)feature)[idx];
    float4 o;
    o.x = f.x * (e.x * sc);
    o.y = f.y * (e.y * sc);
    o.z = f.z * (e.z * sc);
    o.w = f.w * (e.w * sc);
    ((float4*)out)[idx] = o;
}

extern "C" void kernel_launch(void* const* d_in, const int* in_sizes, int n_in,
                              void* d_out, int out_size, void* d_ws, size_t ws_size,
                              hipStream_t stream)
{
    const float* feature = (const float*)d_in[0];
    const float* query   = (const float*)d_in[1];
    const float* key     = (const float*)d_in[2];
    const float* Ua_w    = (const float*)d_in[3];
    const float* Ua_b    = (const float*)d_in[4];
    const float* Va_w    = (const float*)d_in[5];
    const float* Va_b    = (const float*)d_in[6];

    // workspace layout
    ushort_t* Whf    = (ushort_t*)d_ws;                     // 512*64 fp16 frag-order
    float* QB        = (float*)(Whf + NP * CH);             // 32*512
    float* Va2       = QB + BSZ * NP;                       // 512
    float* SUMVW     = Va2 + NP;                            // 1 (+pad)
    float* e_part    = SUMVW + 4;                           // 4*32*4096
    float* e_exp     = e_part + (size_t)OSPLIT * BSZ * HW;  // 32*4096
    float* dsum      = e_exp + BSZ * HW;                    // 256

    k_prep<<<(NP * CH) / 256, 256, 0, stream>>>(
        Ua_w, Ua_b, query, Va_w, Whf, QB, Va2, SUMVW);
    k_scores<<<BSZ * 16 * OSPLIT, 256, 0, stream>>>(
        key, Whf, QB, Va2, e_part);
    k_denom<<<BSZ * 8, 256, 0, stream>>>(e_part, SUMVW, Va_b, e_exp, dsum);
    k_scale<<<(BSZ * CH * HW / 4) / 256, 256, 0, stream>>>(
        feature, e_exp, dsum, (float*)d_out);
}